// Round 7
// baseline (234.694 us; speedup 1.0000x reference)
//
#include <hip/hip_runtime.h>

#define B_ 32
#define N_ 8732
#define N2_ 17464
#define N4_ 4366      // float4 per (b,c) plane
#define Q4 1092       // float4 per slice (4 slices; last = 1090)
#define C_ 21
#define NCLS 20
#define K_ 200
#define CONF_T 0.01f
#define NMS_T 0.45f
#define TPB_S 256
#define TPB_N 256
#define POOL_A 768
#define NBINS 1024
#define HB0 0x3C23u   // hi16 of 0.01f

typedef unsigned long long u64;
typedef unsigned int u32;

// ---------------------------------------------------------------------------
// Kernel 1 (FROZEN): softmax over C=21 -> transposed [B, NCLS, 2N]
// ---------------------------------------------------------------------------
__global__ __launch_bounds__(TPB_S) void softmax_kernel(
    const float* __restrict__ conf1, const float* __restrict__ conf2,
    float* __restrict__ scores)
{
  __shared__ float lds[TPB_S * C_];   // 21 KB
  const int t = threadIdx.x;
  const int tile = blockIdx.x * TPB_S;
  const int b = blockIdx.y;
  const int view = blockIdx.z;
  int cnt = N_ - tile; if (cnt > TPB_S) cnt = TPB_S;
  const float* conf = view ? conf2 : conf1;
  const float4* src = (const float4*)(conf + ((size_t)b * N_ + tile) * C_);
  float4* l4 = (float4*)lds;
  const int n4 = (cnt * C_) >> 2;
  for (int i = t; i < n4; i += TPB_S) l4[i] = src[i];
  __syncthreads();
  if (t < cnt) {
    float x[C_];
#pragma unroll
    for (int i = 0; i < C_; ++i) x[i] = lds[t * C_ + i];
    float m = x[0];
#pragma unroll
    for (int i = 1; i < C_; ++i) m = fmaxf(m, x[i]);
    float e[C_];
    float sum = 0.0f;
#pragma unroll
    for (int i = 0; i < C_; ++i) { e[i] = __expf(x[i] - m); sum += e[i]; }
    float inv = 1.0f / sum;
#pragma unroll
    for (int c = 1; c < C_; ++c) lds[t * C_ + (c - 1)] = e[c] * inv;
  }
  __syncthreads();
  const int nf4 = cnt >> 2;
  const int tot = NCLS * nf4;
  float* base = scores + ((size_t)b * NCLS) * N2_ + (size_t)view * N_ + tile;
  for (int f = t; f < tot; f += TPB_S) {
    int c, a0;
    if (nf4 == 64) { c = f >> 6; a0 = (f & 63) << 2; }
    else           { c = f / 7;  a0 = (f - c * 7) << 2; }
    float4 o;
    o.x = lds[(a0 + 0) * C_ + c];
    o.y = lds[(a0 + 1) * C_ + c];
    o.z = lds[(a0 + 2) * C_ + c];
    o.w = lds[(a0 + 3) * C_ + c];
    *(float4*)(base + (size_t)c * N2_ + a0) = o;
  }
}

// ---------------------------------------------------------------------------
// Kernel A: per (b,c,slice) exact local top-200. Slice (<=4368 floats) lives
// in float4 v[5] registers. hist -> suffix scan -> cutoff -> ballot-collect
// -> rank-by-count -> write 200 composites. Grid 640*4 blocks, 256 thr.
// ---------------------------------------------------------------------------
__global__ __launch_bounds__(TPB_N) void select_kernel(
    const float* __restrict__ scores, u64* __restrict__ cand)
{
  const int t = threadIdx.x;
  const int lane = t & 63;
  const int wv = t >> 6;
  const int bc = blockIdx.x >> 2;
  const int sl = blockIdx.x & 3;
  const float4* sc4 = (const float4*)(scores + (size_t)bc * N2_);
  const int f4base = sl * Q4;
  const int f4end = (f4base + Q4 < N4_) ? (f4base + Q4) : N4_;

  __shared__ u32 hist[NBINS];      // 4 KB
  __shared__ u64 pool[POOL_A];     // 6 KB
  __shared__ u64 spool[256];       // 2 KB
  __shared__ u32 wtot[4];
  __shared__ u32 sh_sel, sh_Sb, sh_Sn, sh_nc;

  // ---- load slice into registers (20 VGPRs) ----
  float4 v[5];
#pragma unroll
  for (int j = 0; j < 5; ++j) {
    int f4 = f4base + t + j * TPB_N;
    v[j] = (f4 < f4end) ? sc4[f4] : make_float4(0.f, 0.f, 0.f, 0.f);
  }

  // ---- histogram on hi16 bins ----
  for (int h = t; h < NBINS; h += TPB_N) hist[h] = 0u;
  __syncthreads();
#pragma unroll
  for (int j = 0; j < 5; ++j) {
    float ss[4] = {v[j].x, v[j].y, v[j].z, v[j].w};
#pragma unroll
    for (int c2 = 0; c2 < 4; ++c2) {
      float s = ss[c2];
      if (s > CONF_T) {
        u32 bin = (__float_as_uint(s) >> 16) - HB0;
        if (bin > 1023u) bin = 1023u;
        atomicAdd(&hist[bin], 1u);
      }
    }
  }
  __syncthreads();

  // ---- suffix sums S[h]: 4 bins/thread + wave scan ----
  {
    u32 c0 = hist[4 * t + 0], c1 = hist[4 * t + 1], c2b = hist[4 * t + 2], c3 = hist[4 * t + 3];
    u32 T = c0 + c1 + c2b + c3;
    u32 x = T;
#pragma unroll
    for (int off = 1; off < 64; off <<= 1) {
      u32 y = __shfl_down(x, off);
      if (lane + off < 64) x += y;
    }
    if (lane == 0) wtot[wv] = x;
    __syncthreads();
    u32 wafter = 0;
    for (int w = wv + 1; w < 4; ++w) wafter += wtot[w];
    u32 run = (x - T) + wafter;
    u32 S3 = c3 + run, S2 = c2b + S3, S1 = c1 + S2, S0 = c0 + S1;
    hist[4 * t + 0] = S0; hist[4 * t + 1] = S1; hist[4 * t + 2] = S2; hist[4 * t + 3] = S3;
  }
  __syncthreads();

  // ---- boundary bin ----
  const u32 total = hist[0];
  const bool undershoot = (total < (u32)K_);
  u32 hbbin = 0, candTotal = total, Gs = 0;
  if (!undershoot) {
    for (int h = t; h < NBINS; h += TPB_N) {
      u32 Sb = hist[h];
      u32 Sn = (h + 1 < NBINS) ? hist[h + 1] : 0u;
      if (Sb >= (u32)K_ && Sn < (u32)K_) { sh_sel = (u32)h; sh_Sb = Sb; sh_Sn = Sn; }
    }
    __syncthreads();
    hbbin = sh_sel; candTotal = sh_Sb; Gs = sh_Sn;
  }
  const bool fallback = (candTotal > (u32)POOL_A);
  const u32 cutbin = undershoot ? 0u : (fallback ? hbbin + 1u : hbbin);

  // ---- ballot-collect (bin >= cutbin) from registers ----
  if (t == 0) sh_nc = 0u;
  __syncthreads();
#pragma unroll
  for (int j = 0; j < 5; ++j) {
    float ss[4] = {v[j].x, v[j].y, v[j].z, v[j].w};
    int f4 = f4base + t + j * TPB_N;
#pragma unroll
    for (int c2 = 0; c2 < 4; ++c2) {
      float s = ss[c2];
      u32 key = __float_as_uint(s);
      bool pred = false;
      if (f4 < f4end && s > CONF_T) {
        u32 bin = (key >> 16) - HB0;
        if (bin > 1023u) bin = 1023u;
        pred = (bin >= cutbin);
      }
      u64 bal = __ballot(pred);
      if (bal) {
        u32 wb = 0;
        if (lane == 0) wb = atomicAdd(&sh_nc, (u32)__popcll(bal));
        wb = __shfl(wb, 0);
        if (pred) {
          u32 pos = wb + (u32)__popcll(bal & ((1ULL << lane) - 1ULL));
          u32 i = (u32)(f4 * 4 + c2);
          if (pos < (u32)POOL_A)
            pool[pos] = ((u64)key << 32) | (u64)(0xFFFFFFFFu - i);
        }
      }
    }
  }
  __syncthreads();
  u32 nc = sh_nc < (u32)POOL_A ? sh_nc : (u32)POOL_A;

  // ---- fallback (boundary-bin ties overflow pool; ~never for random data) ----
  if (fallback) {
    const u32 G = nc;                    // strict-above count (< 200)
    const u32 need2 = (u32)K_ - G;
    float flat[20];
#pragma unroll
    for (int j = 0; j < 5; ++j) {
      flat[4 * j + 0] = v[j].x; flat[4 * j + 1] = v[j].y;
      flat[4 * j + 2] = v[j].z; flat[4 * j + 3] = v[j].w;
    }
#pragma unroll 1
    for (int j5 = 0; j5 < 20; ++j5) {
      u32 cnt = sh_nc;                   // uniform (after barrier)
      if (cnt > (u32)(POOL_A - TPB_N)) { // reduce pool[G..cnt) to top need2
        spool[t] = 0ULL;
        u64 mine[3]; u32 rr[3]; int np = 0;
        for (int p = (int)G + t; p < (int)cnt; p += TPB_N) { mine[np] = pool[p]; rr[np] = 0; ++np; }
        __syncthreads();
        for (int q = (int)G; q < (int)cnt; ++q) {
          u64 pk = pool[q];
          for (int a = 0; a < np; ++a) rr[a] += (pk > mine[a]) ? 1u : 0u;
        }
        for (int a = 0; a < np; ++a) if (rr[a] < need2) spool[rr[a]] = mine[a];
        __syncthreads();
        u32 kept = (cnt - G) < need2 ? (cnt - G) : need2;
        for (int r = t; r < (int)kept; r += TPB_N) pool[G + r] = spool[r];
        if (t == 0) sh_nc = G + kept;
        __syncthreads();
      }
      int q = j5 >> 2, c2 = j5 & 3;
      float s = flat[j5];
      int f4 = f4base + t + q * TPB_N;
      u32 key = __float_as_uint(s);
      bool pred = false;
      if (f4 < f4end && s > CONF_T) {
        u32 bin = (key >> 16) - HB0;
        if (bin > 1023u) bin = 1023u;
        pred = (bin == hbbin);
      }
      u64 bal = __ballot(pred);
      u32 wb = 0;
      if (bal) {
        if (lane == 0) wb = atomicAdd(&sh_nc, (u32)__popcll(bal));
        wb = __shfl(wb, 0);
      }
      if (pred) {
        u32 pos = wb + (u32)__popcll(bal & ((1ULL << lane) - 1ULL));
        u32 i = (u32)(f4 * 4 + c2);
        if (pos < (u32)POOL_A)
          pool[pos] = ((u64)key << 32) | (u64)(0xFFFFFFFFu - i);
      }
      __syncthreads();
    }
    nc = sh_nc < (u32)POOL_A ? sh_nc : (u32)POOL_A;
  }

  // ---- rank-by-count -> exact local top-200 ----
  spool[t] = 0ULL;
  u64 m0 = (t < (int)nc) ? pool[t] : 0ULL;
  u64 m1 = (t + 256 < (int)nc) ? pool[t + 256] : 0ULL;
  u64 m2 = (t + 512 < (int)nc) ? pool[t + 512] : 0ULL;
  __syncthreads();
  u32 r0 = 0, r1 = 0, r2 = 0;
  for (u32 k = 0; k < nc; ++k) {
    u64 pk = pool[k];
    r0 += (pk > m0) ? 1u : 0u;
    r1 += (pk > m1) ? 1u : 0u;
    r2 += (pk > m2) ? 1u : 0u;
  }
  if (m0 != 0ULL && r0 < (u32)K_) spool[r0] = m0;
  if (m1 != 0ULL && r1 < (u32)K_) spool[r1] = m1;
  if (m2 != 0ULL && r2 < (u32)K_) spool[r2] = m2;
  __syncthreads();
  if (t < K_) cand[(size_t)blockIdx.x * K_ + t] = spool[t];
}

// ---------------------------------------------------------------------------
// Kernel B: per (b,c). Merge 4x200 slice candidates -> exact top-200 ->
// decode -> IoU bitmask -> greedy scan -> compact. 640 blocks, 256 thr.
// ---------------------------------------------------------------------------
__global__ __launch_bounds__(TPB_N) void nms_kernel(
    const u64* __restrict__ cand,
    const float4* __restrict__ loc1,
    const float4* __restrict__ loc2,
    const float4* __restrict__ dbox,
    float* __restrict__ out)
{
  const int t = threadIdx.x;
  const int lane = t & 63;
  const int wv = t >> 6;
  const int bc = blockIdx.x;
  const int bimg = bc / NCLS;
  const int cls = 1 + (bc % NCLS);

  __shared__ u64 pool[800];              // 6.4 KB
  __shared__ u64 spool[256];             // 2 KB
  __shared__ float4 bb[K_];              // 3.2 KB
  __shared__ float bar[K_];
  __shared__ u64 rowmask[K_][4];         // 6.4 KB
  __shared__ u64 validmask[4];
  __shared__ u64 keepmask[4];

  for (int i = t; i < 800; i += TPB_N) pool[i] = cand[(size_t)bc * 800 + i];
  spool[t] = 0ULL;
  __syncthreads();

  // ---- rank-by-count merge: 800 -> exact top-200 ----
  u64 m0 = pool[t], m1 = pool[t + 256], m2 = pool[t + 512];
  u64 m3 = (t < 32) ? pool[t + 768] : 0ULL;
  u32 r0 = 0, r1 = 0, r2 = 0, r3 = 0;
  for (int k = 0; k < 800; ++k) {
    u64 pk = pool[k];
    r0 += (pk > m0) ? 1u : 0u;
    r1 += (pk > m1) ? 1u : 0u;
    r2 += (pk > m2) ? 1u : 0u;
    r3 += (pk > m3) ? 1u : 0u;
  }
  if (m0 != 0ULL && r0 < (u32)K_) spool[r0] = m0;
  if (m1 != 0ULL && r1 < (u32)K_) spool[r1] = m1;
  if (m2 != 0ULL && r2 < (u32)K_) spool[r2] = m2;
  if (m3 != 0ULL && r3 < (u32)K_) spool[r3] = m3;
  __syncthreads();
  // spool[0..199] == exact top_k (desc score, ties by ascending index)

  // ---- decode boxes for top-200 ----
  float x1 = 0.f, y1 = 0.f, x2 = 0.f, y2 = 0.f, area = 0.f, scv = 0.f;
  if (t < K_) {
    u64 e = spool[t];
    u32 kb = (u32)(e >> 32);
    if (kb != 0u) {
      scv = __uint_as_float(kb);
      u32 idx = 0xFFFFFFFFu - (u32)(e & 0xFFFFFFFFu);
      int nn = (idx < (u32)N_) ? (int)idx : (int)(idx - N_);
      float4 l = (idx < (u32)N_) ? loc1[(size_t)bimg * N_ + nn]
                                 : loc2[(size_t)bimg * N_ + nn];
      float4 d = dbox[nn];
      float cx = d.x + l.x * 0.1f * d.z;
      float cy = d.y + l.y * 0.1f * d.w;
      float w = d.z * __expf(l.z * 0.2f);
      float h = d.w * __expf(l.w * 0.2f);
      x1 = cx - w * 0.5f; y1 = cy - h * 0.5f;
      x2 = cx + w * 0.5f; y2 = cy + h * 0.5f;
      if (idx >= (u32)N_) {   // horizontal flip of second (TTA) view
        float tmp = 1.0f - x2; x2 = 1.0f - x1; x1 = tmp;
      }
      area = (x2 - x1) * (y2 - y1);
    }
    bb[t] = make_float4(x1, y1, x2, y2);
    bar[t] = area;
  }
  {
    bool myvalid = (t < K_) && (scv > CONF_T);
    u64 bal = __ballot(myvalid);
    if (lane == 0) validmask[wv] = bal;
  }
  __syncthreads();

  // ---- IoU>thresh bitmask rows ----
  if (t < K_) {
    float4 mb = bb[t];
    float ma = bar[t];
#pragma unroll
    for (int w2 = 0; w2 < 4; ++w2) {
      const int ce = (w2 == 3) ? (K_ - 192) : 64;
      u64 mw = 0;
      for (int j = 0; j < ce; ++j) {
        int k2 = w2 * 64 + j;
        float4 ob = bb[k2];
        float ox1 = fmaxf(mb.x, ob.x);
        float oy1 = fmaxf(mb.y, ob.y);
        float ox2 = fminf(mb.z, ob.z);
        float oy2 = fminf(mb.w, ob.w);
        float inter = fmaxf(ox2 - ox1, 0.f) * fmaxf(oy2 - oy1, 0.f);
        float uni = ma + bar[k2] - inter;
        u64 bit = (inter > NMS_T * uni) ? 1ULL : 0ULL;
        mw |= bit << j;
      }
      rowmask[t][w2] = mw;
    }
  }
  __syncthreads();

  // ---- sequential greedy scan: wave 0, replicated register state ----
  if (t < 64) {
    u64 v0 = validmask[0], v1 = validmask[1], v2 = validmask[2], v3 = validmask[3];
    u64 s0 = 0, s1 = 0, s2 = 0, s3 = 0;
    u64 k0 = 0, k1 = 0, k2m = 0, k3 = 0;
#pragma unroll 8
    for (int j = 0; j < K_; ++j) {
      u64 q0 = rowmask[j][0], q1 = rowmask[j][1], q2 = rowmask[j][2], q3 = rowmask[j][3];
      int q = j >> 6;
      u64 bit = 1ULL << (j & 63);
      u64 vw = (q == 0) ? v0 : (q == 1) ? v1 : (q == 2) ? v2 : v3;
      u64 sw = (q == 0) ? s0 : (q == 1) ? s1 : (q == 2) ? s2 : s3;
      if ((vw & bit) && !(sw & bit)) {
        s0 |= q0; s1 |= q1; s2 |= q2; s3 |= q3;
        if (q == 0) k0 |= bit; else if (q == 1) k1 |= bit;
        else if (q == 2) k2m |= bit; else k3 |= bit;
      }
    }
    if (t == 0) { keepmask[0] = k0; keepmask[1] = k1; keepmask[2] = k2m; keepmask[3] = k3; }
  }
  __syncthreads();

  // ---- compact kept entries ----
  if (t < K_) {
    int q = t >> 6, bitp = t & 63;
    u64 kw = keepmask[q];
    if ((kw >> bitp) & 1ULL) {
      int pos = (int)__popcll(kw & ((1ULL << bitp) - 1ULL));
      for (int w2 = 0; w2 < q; ++w2) pos += (int)__popcll(keepmask[w2]);
      float* o = out + ((((size_t)bimg * C_) + cls) * K_ + (size_t)pos) * 5;
      o[0] = scv; o[1] = x1; o[2] = y1; o[3] = x2; o[4] = y2;
    }
  }
}

extern "C" void kernel_launch(void* const* d_in, const int* in_sizes, int n_in,
                              void* d_out, int out_size, void* d_ws, size_t ws_size,
                              hipStream_t stream) {
  const float* loc1 = (const float*)d_in[0];
  const float* conf1 = (const float*)d_in[1];
  const float* loc2 = (const float*)d_in[2];
  const float* conf2 = (const float*)d_in[3];
  const float* dbox = (const float*)d_in[4];
  float* out = (float*)d_out;
  float* scores = (float*)d_ws;                              // 44,707,840 B
  u64* cand = (u64*)((char*)d_ws + 44707840);                // 640*4*200*8 = 4,096,000 B

  hipMemsetAsync(d_out, 0, (size_t)out_size * sizeof(float), stream);

  dim3 g1((N_ + TPB_S - 1) / TPB_S, B_, 2);
  softmax_kernel<<<g1, TPB_S, 0, stream>>>(conf1, conf2, scores);

  select_kernel<<<B_ * NCLS * 4, TPB_N, 0, stream>>>(scores, cand);

  nms_kernel<<<B_ * NCLS, TPB_N, 0, stream>>>(
      cand, (const float4*)loc1, (const float4*)loc2, (const float4*)dbox, out);
}

// Round 8
// 197.687 us; speedup vs baseline: 1.1872x; 1.1872x over previous
//
#include <hip/hip_runtime.h>

#define B_ 32
#define N_ 8732
#define N2_ 17464
#define N4_ 4366      // float4 per (b,c) plane
#define Q4 1092       // float4 per slice (4 slices; last = 1090)
#define C_ 21
#define NCLS 20
#define K_ 200
#define CONF_T 0.01f
#define NMS_T 0.45f
#define TPB_S 256
#define TPB_N 256
#define POOL_A 768
#define NBINS 1024
#define HB0 0x3C23u   // hi16 of 0.01f

typedef unsigned long long u64;
typedef unsigned int u32;

// ---------------------------------------------------------------------------
// Kernel 1 (FROZEN): softmax over C=21 -> transposed [B, NCLS, 2N]
// ---------------------------------------------------------------------------
__global__ __launch_bounds__(TPB_S) void softmax_kernel(
    const float* __restrict__ conf1, const float* __restrict__ conf2,
    float* __restrict__ scores)
{
  __shared__ float lds[TPB_S * C_];   // 21 KB
  const int t = threadIdx.x;
  const int tile = blockIdx.x * TPB_S;
  const int b = blockIdx.y;
  const int view = blockIdx.z;
  int cnt = N_ - tile; if (cnt > TPB_S) cnt = TPB_S;
  const float* conf = view ? conf2 : conf1;
  const float4* src = (const float4*)(conf + ((size_t)b * N_ + tile) * C_);
  float4* l4 = (float4*)lds;
  const int n4 = (cnt * C_) >> 2;
  for (int i = t; i < n4; i += TPB_S) l4[i] = src[i];
  __syncthreads();
  if (t < cnt) {
    float x[C_];
#pragma unroll
    for (int i = 0; i < C_; ++i) x[i] = lds[t * C_ + i];
    float m = x[0];
#pragma unroll
    for (int i = 1; i < C_; ++i) m = fmaxf(m, x[i]);
    float e[C_];
    float sum = 0.0f;
#pragma unroll
    for (int i = 0; i < C_; ++i) { e[i] = __expf(x[i] - m); sum += e[i]; }
    float inv = 1.0f / sum;
#pragma unroll
    for (int c = 1; c < C_; ++c) lds[t * C_ + (c - 1)] = e[c] * inv;
  }
  __syncthreads();
  const int nf4 = cnt >> 2;
  const int tot = NCLS * nf4;
  float* base = scores + ((size_t)b * NCLS) * N2_ + (size_t)view * N_ + tile;
  for (int f = t; f < tot; f += TPB_S) {
    int c, a0;
    if (nf4 == 64) { c = f >> 6; a0 = (f & 63) << 2; }
    else           { c = f / 7;  a0 = (f - c * 7) << 2; }
    float4 o;
    o.x = lds[(a0 + 0) * C_ + c];
    o.y = lds[(a0 + 1) * C_ + c];
    o.z = lds[(a0 + 2) * C_ + c];
    o.w = lds[(a0 + 3) * C_ + c];
    *(float4*)(base + (size_t)c * N2_ + a0) = o;
  }
}

// ---------------------------------------------------------------------------
// Kernel A: per (b,c,slice) exact local top-200, emitted SORTED descending.
// Grid 640*4 blocks, 256 thr.
// ---------------------------------------------------------------------------
__global__ __launch_bounds__(TPB_N) void select_kernel(
    const float* __restrict__ scores, u64* __restrict__ cand)
{
  const int t = threadIdx.x;
  const int lane = t & 63;
  const int wv = t >> 6;
  const int bc = blockIdx.x >> 2;
  const int sl = blockIdx.x & 3;
  const float4* sc4 = (const float4*)(scores + (size_t)bc * N2_);
  const int f4base = sl * Q4;
  const int f4end = (f4base + Q4 < N4_) ? (f4base + Q4) : N4_;

  __shared__ u32 hist[NBINS];      // 4 KB
  __shared__ u64 pool[POOL_A];     // 6 KB
  __shared__ u64 spool[256];       // 2 KB
  __shared__ u32 wtot[4];
  __shared__ u32 sh_sel, sh_Sb, sh_Sn, sh_nc;

  // ---- load slice into registers (20 VGPRs) ----
  float4 v[5];
#pragma unroll
  for (int j = 0; j < 5; ++j) {
    int f4 = f4base + t + j * TPB_N;
    v[j] = (f4 < f4end) ? sc4[f4] : make_float4(0.f, 0.f, 0.f, 0.f);
  }

  // ---- histogram on hi16 bins ----
  for (int h = t; h < NBINS; h += TPB_N) hist[h] = 0u;
  __syncthreads();
#pragma unroll
  for (int j = 0; j < 5; ++j) {
    float ss[4] = {v[j].x, v[j].y, v[j].z, v[j].w};
#pragma unroll
    for (int c2 = 0; c2 < 4; ++c2) {
      float s = ss[c2];
      if (s > CONF_T) {
        u32 bin = (__float_as_uint(s) >> 16) - HB0;
        if (bin > 1023u) bin = 1023u;
        atomicAdd(&hist[bin], 1u);
      }
    }
  }
  __syncthreads();

  // ---- suffix sums S[h]: 4 bins/thread + wave scan ----
  {
    u32 c0 = hist[4 * t + 0], c1 = hist[4 * t + 1], c2b = hist[4 * t + 2], c3 = hist[4 * t + 3];
    u32 T = c0 + c1 + c2b + c3;
    u32 x = T;
#pragma unroll
    for (int off = 1; off < 64; off <<= 1) {
      u32 y = __shfl_down(x, off);
      if (lane + off < 64) x += y;
    }
    if (lane == 0) wtot[wv] = x;
    __syncthreads();
    u32 wafter = 0;
    for (int w = wv + 1; w < 4; ++w) wafter += wtot[w];
    u32 run = (x - T) + wafter;
    u32 S3 = c3 + run, S2 = c2b + S3, S1 = c1 + S2, S0 = c0 + S1;
    hist[4 * t + 0] = S0; hist[4 * t + 1] = S1; hist[4 * t + 2] = S2; hist[4 * t + 3] = S3;
  }
  __syncthreads();

  // ---- boundary bin ----
  const u32 total = hist[0];
  const bool undershoot = (total < (u32)K_);
  u32 hbbin = 0, candTotal = total;
  if (!undershoot) {
    for (int h = t; h < NBINS; h += TPB_N) {
      u32 Sb = hist[h];
      u32 Sn = (h + 1 < NBINS) ? hist[h + 1] : 0u;
      if (Sb >= (u32)K_ && Sn < (u32)K_) { sh_sel = (u32)h; sh_Sb = Sb; sh_Sn = Sn; }
    }
    __syncthreads();
    hbbin = sh_sel; candTotal = sh_Sb;
  }
  const bool fallback = (candTotal > (u32)POOL_A);
  const u32 cutbin = undershoot ? 0u : (fallback ? hbbin + 1u : hbbin);

  // ---- ballot-collect (bin >= cutbin) from registers ----
  if (t == 0) sh_nc = 0u;
  __syncthreads();
#pragma unroll
  for (int j = 0; j < 5; ++j) {
    float ss[4] = {v[j].x, v[j].y, v[j].z, v[j].w};
    int f4 = f4base + t + j * TPB_N;
#pragma unroll
    for (int c2 = 0; c2 < 4; ++c2) {
      float s = ss[c2];
      u32 key = __float_as_uint(s);
      bool pred = false;
      if (f4 < f4end && s > CONF_T) {
        u32 bin = (key >> 16) - HB0;
        if (bin > 1023u) bin = 1023u;
        pred = (bin >= cutbin);
      }
      u64 bal = __ballot(pred);
      if (bal) {
        u32 wb = 0;
        if (lane == 0) wb = atomicAdd(&sh_nc, (u32)__popcll(bal));
        wb = __shfl(wb, 0);
        if (pred) {
          u32 pos = wb + (u32)__popcll(bal & ((1ULL << lane) - 1ULL));
          u32 i = (u32)(f4 * 4 + c2);
          if (pos < (u32)POOL_A)
            pool[pos] = ((u64)key << 32) | (u64)(0xFFFFFFFFu - i);
        }
      }
    }
  }
  __syncthreads();
  u32 nc = sh_nc < (u32)POOL_A ? sh_nc : (u32)POOL_A;

  // ---- fallback (boundary-bin ties overflow pool; ~never for random data) ----
  if (fallback) {
    const u32 G = nc;                    // strict-above count (< 200)
    const u32 need2 = (u32)K_ - G;
    float flat[20];
#pragma unroll
    for (int j = 0; j < 5; ++j) {
      flat[4 * j + 0] = v[j].x; flat[4 * j + 1] = v[j].y;
      flat[4 * j + 2] = v[j].z; flat[4 * j + 3] = v[j].w;
    }
#pragma unroll 1
    for (int j5 = 0; j5 < 20; ++j5) {
      u32 cnt = sh_nc;                   // uniform (after barrier)
      if (cnt > (u32)(POOL_A - TPB_N)) { // reduce pool[G..cnt) to top need2
        spool[t] = 0ULL;
        u64 mine[3]; u32 rr[3]; int np = 0;
        for (int p = (int)G + t; p < (int)cnt; p += TPB_N) { mine[np] = pool[p]; rr[np] = 0; ++np; }
        __syncthreads();
        for (int q = (int)G; q < (int)cnt; ++q) {
          u64 pk = pool[q];
          for (int a = 0; a < np; ++a) rr[a] += (pk > mine[a]) ? 1u : 0u;
        }
        for (int a = 0; a < np; ++a) if (rr[a] < need2) spool[rr[a]] = mine[a];
        __syncthreads();
        u32 kept = (cnt - G) < need2 ? (cnt - G) : need2;
        for (int r = t; r < (int)kept; r += TPB_N) pool[G + r] = spool[r];
        if (t == 0) sh_nc = G + kept;
        __syncthreads();
      }
      int q = j5 >> 2, c2 = j5 & 3;
      float s = flat[j5];
      int f4 = f4base + t + q * TPB_N;
      u32 key = __float_as_uint(s);
      bool pred = false;
      if (f4 < f4end && s > CONF_T) {
        u32 bin = (key >> 16) - HB0;
        if (bin > 1023u) bin = 1023u;
        pred = (bin == hbbin);
      }
      u64 bal = __ballot(pred);
      u32 wb = 0;
      if (bal) {
        if (lane == 0) wb = atomicAdd(&sh_nc, (u32)__popcll(bal));
        wb = __shfl(wb, 0);
      }
      if (pred) {
        u32 pos = wb + (u32)__popcll(bal & ((1ULL << lane) - 1ULL));
        u32 i = (u32)(f4 * 4 + c2);
        if (pos < (u32)POOL_A)
          pool[pos] = ((u64)key << 32) | (u64)(0xFFFFFFFFu - i);
      }
      __syncthreads();
    }
    nc = sh_nc < (u32)POOL_A ? sh_nc : (u32)POOL_A;
  }

  // ---- rank-by-count (batched x4) -> exact sorted local top-200 ----
  spool[t] = 0ULL;
  u64 m0 = (t < (int)nc) ? pool[t] : 0ULL;
  u64 m1 = (t + 256 < (int)nc) ? pool[t + 256] : 0ULL;
  u64 m2 = (t + 512 < (int)nc) ? pool[t + 512] : 0ULL;
  __syncthreads();
  u32 r0 = 0, r1 = 0, r2 = 0;
  u32 k = 0;
  for (; k + 4 <= nc; k += 4) {
    u64 p0 = pool[k], p1 = pool[k + 1], p2 = pool[k + 2], p3 = pool[k + 3];
    r0 += (u32)(p0 > m0) + (u32)(p1 > m0) + (u32)(p2 > m0) + (u32)(p3 > m0);
    r1 += (u32)(p0 > m1) + (u32)(p1 > m1) + (u32)(p2 > m1) + (u32)(p3 > m1);
    r2 += (u32)(p0 > m2) + (u32)(p1 > m2) + (u32)(p2 > m2) + (u32)(p3 > m2);
  }
  for (; k < nc; ++k) {
    u64 pk = pool[k];
    r0 += (u32)(pk > m0); r1 += (u32)(pk > m1); r2 += (u32)(pk > m2);
  }
  if (m0 != 0ULL && r0 < (u32)K_) spool[r0] = m0;
  if (m1 != 0ULL && r1 < (u32)K_) spool[r1] = m1;
  if (m2 != 0ULL && r2 < (u32)K_) spool[r2] = m2;
  __syncthreads();
  if (t < K_) cand[(size_t)blockIdx.x * K_ + t] = spool[t];
}

// ---------------------------------------------------------------------------
// Kernel B: per (b,c). Binary-search merge of 4 SORTED 200-lists -> exact
// top-200 -> decode -> IoU bitmask -> batched greedy scan -> compact.
// 640 blocks, 256 thr.
// ---------------------------------------------------------------------------
__global__ __launch_bounds__(TPB_N) void nms_kernel(
    const u64* __restrict__ cand,
    const float4* __restrict__ loc1,
    const float4* __restrict__ loc2,
    const float4* __restrict__ dbox,
    float* __restrict__ out)
{
  const int t = threadIdx.x;
  const int lane = t & 63;
  const int wv = t >> 6;
  const int bc = blockIdx.x;
  const int bimg = bc / NCLS;
  const int cls = 1 + (bc % NCLS);

  __shared__ u64 pool[800];              // 6.4 KB: 4 sorted desc segments of 200
  __shared__ u64 spool[256];             // 2 KB
  __shared__ float4 bb[K_];              // 3.2 KB
  __shared__ float bar[K_];
  __shared__ u64 rowmask[K_][4];         // 6.4 KB
  __shared__ u64 validmask[4];
  __shared__ u64 keepmask[4];

  for (int i = t; i < 800; i += TPB_N) pool[i] = cand[(size_t)bc * 800 + i];
  spool[t] = 0ULL;
  __syncthreads();

  // ---- merge: global rank = own rank + binary-search counts in other lists ----
#pragma unroll
  for (int a = 0; a < 4; ++a) {
    int el = t + 256 * a;                // 0..1023
    if (el < 800) {
      int sl = el / 200;
      int r = el - sl * 200;
      u64 e = pool[el];
      if (e != 0ULL) {
        u32 g = (u32)r;                  // own list: exactly r elements greater
#pragma unroll
        for (int o = 0; o < 4; ++o) {
          if (o != sl) {
            const u64* seg = pool + o * 200;
            u32 lo = 0, hi = 200;
#pragma unroll
            for (int s8 = 0; s8 < 8; ++s8) {   // 200 -> <=1 in 8 halvings
              u32 mid = (lo + hi) >> 1;
              bool gt = seg[mid] > e;
              lo = gt ? mid + 1 : lo;
              hi = gt ? hi : mid;
            }
            if (lo < hi && seg[lo] > e) ++lo;
            g += lo;                     // count of seg elements > e
          }
        }
        if (g < (u32)K_) spool[g] = e;   // ranks distinct (keys unique) -> exact
      }
    }
  }
  __syncthreads();
  // spool[0..199] == exact top_k (desc score, ties by ascending index)

  // ---- decode boxes for top-200 ----
  float x1 = 0.f, y1 = 0.f, x2 = 0.f, y2 = 0.f, area = 0.f, scv = 0.f;
  if (t < K_) {
    u64 e = spool[t];
    u32 kb = (u32)(e >> 32);
    if (kb != 0u) {
      scv = __uint_as_float(kb);
      u32 idx = 0xFFFFFFFFu - (u32)(e & 0xFFFFFFFFu);
      int nn = (idx < (u32)N_) ? (int)idx : (int)(idx - N_);
      float4 l = (idx < (u32)N_) ? loc1[(size_t)bimg * N_ + nn]
                                 : loc2[(size_t)bimg * N_ + nn];
      float4 d = dbox[nn];
      float cx = d.x + l.x * 0.1f * d.z;
      float cy = d.y + l.y * 0.1f * d.w;
      float w = d.z * __expf(l.z * 0.2f);
      float h = d.w * __expf(l.w * 0.2f);
      x1 = cx - w * 0.5f; y1 = cy - h * 0.5f;
      x2 = cx + w * 0.5f; y2 = cy + h * 0.5f;
      if (idx >= (u32)N_) {   // horizontal flip of second (TTA) view
        float tmp = 1.0f - x2; x2 = 1.0f - x1; x1 = tmp;
      }
      area = (x2 - x1) * (y2 - y1);
    }
    bb[t] = make_float4(x1, y1, x2, y2);
    bar[t] = area;
  }
  {
    bool myvalid = (t < K_) && (scv > CONF_T);
    u64 bal = __ballot(myvalid);
    if (lane == 0) validmask[wv] = bal;
  }
  __syncthreads();

  // ---- IoU>thresh bitmask rows ----
  if (t < K_) {
    float4 mb = bb[t];
    float ma = bar[t];
#pragma unroll
    for (int w2 = 0; w2 < 4; ++w2) {
      const int ce = (w2 == 3) ? (K_ - 192) : 64;
      u64 mw = 0;
#pragma unroll 8
      for (int j = 0; j < ce; ++j) {
        int k2 = w2 * 64 + j;
        float4 ob = bb[k2];
        float ox1 = fmaxf(mb.x, ob.x);
        float oy1 = fmaxf(mb.y, ob.y);
        float ox2 = fminf(mb.z, ob.z);
        float oy2 = fminf(mb.w, ob.w);
        float inter = fmaxf(ox2 - ox1, 0.f) * fmaxf(oy2 - oy1, 0.f);
        float uni = ma + bar[k2] - inter;
        u64 bit = (inter > NMS_T * uni) ? 1ULL : 0ULL;
        mw |= bit << j;
      }
      rowmask[t][w2] = mw;
    }
  }
  __syncthreads();

  // ---- sequential greedy scan: wave 0, batched LDS loads (4 rows/batch) ----
  if (t < 64) {
    u64 v0 = validmask[0], v1 = validmask[1], v2 = validmask[2], v3 = validmask[3];
    u64 s0 = 0, s1 = 0, s2 = 0, s3 = 0;
    u64 k0 = 0, k1 = 0, k2m = 0, k3 = 0;
    for (int j0 = 0; j0 < K_; j0 += 4) {     // K_ % 4 == 0
      u64 q[4][4];
#pragma unroll
      for (int u = 0; u < 4; ++u) {
        q[u][0] = rowmask[j0 + u][0]; q[u][1] = rowmask[j0 + u][1];
        q[u][2] = rowmask[j0 + u][2]; q[u][3] = rowmask[j0 + u][3];
      }
#pragma unroll
      for (int u = 0; u < 4; ++u) {
        int j = j0 + u;
        int qw = j >> 6;
        u64 bit = 1ULL << (j & 63);
        u64 vw = (qw == 0) ? v0 : (qw == 1) ? v1 : (qw == 2) ? v2 : v3;
        u64 sw = (qw == 0) ? s0 : (qw == 1) ? s1 : (qw == 2) ? s2 : s3;
        if ((vw & bit) && !(sw & bit)) {
          s0 |= q[u][0]; s1 |= q[u][1]; s2 |= q[u][2]; s3 |= q[u][3];
          if (qw == 0) k0 |= bit; else if (qw == 1) k1 |= bit;
          else if (qw == 2) k2m |= bit; else k3 |= bit;
        }
      }
    }
    if (t == 0) { keepmask[0] = k0; keepmask[1] = k1; keepmask[2] = k2m; keepmask[3] = k3; }
  }
  __syncthreads();

  // ---- compact kept entries ----
  if (t < K_) {
    int q = t >> 6, bitp = t & 63;
    u64 kw = keepmask[q];
    if ((kw >> bitp) & 1ULL) {
      int pos = (int)__popcll(kw & ((1ULL << bitp) - 1ULL));
      for (int w2 = 0; w2 < q; ++w2) pos += (int)__popcll(keepmask[w2]);
      float* o = out + ((((size_t)bimg * C_) + cls) * K_ + (size_t)pos) * 5;
      o[0] = scv; o[1] = x1; o[2] = y1; o[3] = x2; o[4] = y2;
    }
  }
}

extern "C" void kernel_launch(void* const* d_in, const int* in_sizes, int n_in,
                              void* d_out, int out_size, void* d_ws, size_t ws_size,
                              hipStream_t stream) {
  const float* loc1 = (const float*)d_in[0];
  const float* conf1 = (const float*)d_in[1];
  const float* loc2 = (const float*)d_in[2];
  const float* conf2 = (const float*)d_in[3];
  const float* dbox = (const float*)d_in[4];
  float* out = (float*)d_out;
  float* scores = (float*)d_ws;                              // 44,707,840 B
  u64* cand = (u64*)((char*)d_ws + 44707840);                // 640*4*200*8 = 4,096,000 B

  hipMemsetAsync(d_out, 0, (size_t)out_size * sizeof(float), stream);

  dim3 g1((N_ + TPB_S - 1) / TPB_S, B_, 2);
  softmax_kernel<<<g1, TPB_S, 0, stream>>>(conf1, conf2, scores);

  select_kernel<<<B_ * NCLS * 4, TPB_N, 0, stream>>>(scores, cand);

  nms_kernel<<<B_ * NCLS, TPB_N, 0, stream>>>(
      cand, (const float4*)loc1, (const float4*)loc2, (const float4*)dbox, out);
}

// Round 9
// 197.414 us; speedup vs baseline: 1.1888x; 1.0014x over previous
//
#include <hip/hip_runtime.h>

#define B_ 32
#define N_ 8732
#define N2_ 17464
#define N4_ 4366      // float4 per (b,c) plane
#define Q4 1092       // float4 per slice (4 slices; last = 1090)
#define C_ 21
#define NCLS 20
#define K_ 200
#define CONF_T 0.01f
#define NMS_T 0.45f
#define TPB_S 256
#define TPB_A 256
#define TPB_N 512
#define POOL_A 768
#define NBINS 1024
#define HB0 0x3C23u   // hi16 of 0.01f

typedef unsigned long long u64;
typedef unsigned int u32;

// ---------------------------------------------------------------------------
// Kernel 1 (FROZEN): softmax over C=21 -> transposed [B, NCLS, 2N]
// ---------------------------------------------------------------------------
__global__ __launch_bounds__(TPB_S) void softmax_kernel(
    const float* __restrict__ conf1, const float* __restrict__ conf2,
    float* __restrict__ scores)
{
  __shared__ float lds[TPB_S * C_];   // 21 KB
  const int t = threadIdx.x;
  const int tile = blockIdx.x * TPB_S;
  const int b = blockIdx.y;
  const int view = blockIdx.z;
  int cnt = N_ - tile; if (cnt > TPB_S) cnt = TPB_S;
  const float* conf = view ? conf2 : conf1;
  const float4* src = (const float4*)(conf + ((size_t)b * N_ + tile) * C_);
  float4* l4 = (float4*)lds;
  const int n4 = (cnt * C_) >> 2;
  for (int i = t; i < n4; i += TPB_S) l4[i] = src[i];
  __syncthreads();
  if (t < cnt) {
    float x[C_];
#pragma unroll
    for (int i = 0; i < C_; ++i) x[i] = lds[t * C_ + i];
    float m = x[0];
#pragma unroll
    for (int i = 1; i < C_; ++i) m = fmaxf(m, x[i]);
    float e[C_];
    float sum = 0.0f;
#pragma unroll
    for (int i = 0; i < C_; ++i) { e[i] = __expf(x[i] - m); sum += e[i]; }
    float inv = 1.0f / sum;
#pragma unroll
    for (int c = 1; c < C_; ++c) lds[t * C_ + (c - 1)] = e[c] * inv;
  }
  __syncthreads();
  const int nf4 = cnt >> 2;
  const int tot = NCLS * nf4;
  float* base = scores + ((size_t)b * NCLS) * N2_ + (size_t)view * N_ + tile;
  for (int f = t; f < tot; f += TPB_S) {
    int c, a0;
    if (nf4 == 64) { c = f >> 6; a0 = (f & 63) << 2; }
    else           { c = f / 7;  a0 = (f - c * 7) << 2; }
    float4 o;
    o.x = lds[(a0 + 0) * C_ + c];
    o.y = lds[(a0 + 1) * C_ + c];
    o.z = lds[(a0 + 2) * C_ + c];
    o.w = lds[(a0 + 3) * C_ + c];
    *(float4*)(base + (size_t)c * N2_ + a0) = o;
  }
}

// ---------------------------------------------------------------------------
// Kernel A (FROZEN from R8): per (b,c,slice) exact local top-200, SORTED desc.
// Grid 640*4 blocks, 256 thr.
// ---------------------------------------------------------------------------
__global__ __launch_bounds__(TPB_A) void select_kernel(
    const float* __restrict__ scores, u64* __restrict__ cand)
{
  const int t = threadIdx.x;
  const int lane = t & 63;
  const int wv = t >> 6;
  const int bc = blockIdx.x >> 2;
  const int sl = blockIdx.x & 3;
  const float4* sc4 = (const float4*)(scores + (size_t)bc * N2_);
  const int f4base = sl * Q4;
  const int f4end = (f4base + Q4 < N4_) ? (f4base + Q4) : N4_;

  __shared__ u32 hist[NBINS];      // 4 KB
  __shared__ u64 pool[POOL_A];     // 6 KB
  __shared__ u64 spool[256];       // 2 KB
  __shared__ u32 wtot[4];
  __shared__ u32 sh_sel, sh_Sb, sh_Sn, sh_nc;

  float4 v[5];
#pragma unroll
  for (int j = 0; j < 5; ++j) {
    int f4 = f4base + t + j * TPB_A;
    v[j] = (f4 < f4end) ? sc4[f4] : make_float4(0.f, 0.f, 0.f, 0.f);
  }

  for (int h = t; h < NBINS; h += TPB_A) hist[h] = 0u;
  __syncthreads();
#pragma unroll
  for (int j = 0; j < 5; ++j) {
    float ss[4] = {v[j].x, v[j].y, v[j].z, v[j].w};
#pragma unroll
    for (int c2 = 0; c2 < 4; ++c2) {
      float s = ss[c2];
      if (s > CONF_T) {
        u32 bin = (__float_as_uint(s) >> 16) - HB0;
        if (bin > 1023u) bin = 1023u;
        atomicAdd(&hist[bin], 1u);
      }
    }
  }
  __syncthreads();

  {
    u32 c0 = hist[4 * t + 0], c1 = hist[4 * t + 1], c2b = hist[4 * t + 2], c3 = hist[4 * t + 3];
    u32 T = c0 + c1 + c2b + c3;
    u32 x = T;
#pragma unroll
    for (int off = 1; off < 64; off <<= 1) {
      u32 y = __shfl_down(x, off);
      if (lane + off < 64) x += y;
    }
    if (lane == 0) wtot[wv] = x;
    __syncthreads();
    u32 wafter = 0;
    for (int w = wv + 1; w < 4; ++w) wafter += wtot[w];
    u32 run = (x - T) + wafter;
    u32 S3 = c3 + run, S2 = c2b + S3, S1 = c1 + S2, S0 = c0 + S1;
    hist[4 * t + 0] = S0; hist[4 * t + 1] = S1; hist[4 * t + 2] = S2; hist[4 * t + 3] = S3;
  }
  __syncthreads();

  const u32 total = hist[0];
  const bool undershoot = (total < (u32)K_);
  u32 hbbin = 0, candTotal = total;
  if (!undershoot) {
    for (int h = t; h < NBINS; h += TPB_A) {
      u32 Sb = hist[h];
      u32 Sn = (h + 1 < NBINS) ? hist[h + 1] : 0u;
      if (Sb >= (u32)K_ && Sn < (u32)K_) { sh_sel = (u32)h; sh_Sb = Sb; sh_Sn = Sn; }
    }
    __syncthreads();
    hbbin = sh_sel; candTotal = sh_Sb;
  }
  const bool fallback = (candTotal > (u32)POOL_A);
  const u32 cutbin = undershoot ? 0u : (fallback ? hbbin + 1u : hbbin);

  if (t == 0) sh_nc = 0u;
  __syncthreads();
#pragma unroll
  for (int j = 0; j < 5; ++j) {
    float ss[4] = {v[j].x, v[j].y, v[j].z, v[j].w};
    int f4 = f4base + t + j * TPB_A;
#pragma unroll
    for (int c2 = 0; c2 < 4; ++c2) {
      float s = ss[c2];
      u32 key = __float_as_uint(s);
      bool pred = false;
      if (f4 < f4end && s > CONF_T) {
        u32 bin = (key >> 16) - HB0;
        if (bin > 1023u) bin = 1023u;
        pred = (bin >= cutbin);
      }
      u64 bal = __ballot(pred);
      if (bal) {
        u32 wb = 0;
        if (lane == 0) wb = atomicAdd(&sh_nc, (u32)__popcll(bal));
        wb = __shfl(wb, 0);
        if (pred) {
          u32 pos = wb + (u32)__popcll(bal & ((1ULL << lane) - 1ULL));
          u32 i = (u32)(f4 * 4 + c2);
          if (pos < (u32)POOL_A)
            pool[pos] = ((u64)key << 32) | (u64)(0xFFFFFFFFu - i);
        }
      }
    }
  }
  __syncthreads();
  u32 nc = sh_nc < (u32)POOL_A ? sh_nc : (u32)POOL_A;

  if (fallback) {
    const u32 G = nc;
    const u32 need2 = (u32)K_ - G;
    float flat[20];
#pragma unroll
    for (int j = 0; j < 5; ++j) {
      flat[4 * j + 0] = v[j].x; flat[4 * j + 1] = v[j].y;
      flat[4 * j + 2] = v[j].z; flat[4 * j + 3] = v[j].w;
    }
#pragma unroll 1
    for (int j5 = 0; j5 < 20; ++j5) {
      u32 cnt = sh_nc;
      if (cnt > (u32)(POOL_A - TPB_A)) {
        spool[t] = 0ULL;
        u64 mine[3]; u32 rr[3]; int np = 0;
        for (int p = (int)G + t; p < (int)cnt; p += TPB_A) { mine[np] = pool[p]; rr[np] = 0; ++np; }
        __syncthreads();
        for (int q = (int)G; q < (int)cnt; ++q) {
          u64 pk = pool[q];
          for (int a = 0; a < np; ++a) rr[a] += (pk > mine[a]) ? 1u : 0u;
        }
        for (int a = 0; a < np; ++a) if (rr[a] < need2) spool[rr[a]] = mine[a];
        __syncthreads();
        u32 kept = (cnt - G) < need2 ? (cnt - G) : need2;
        for (int r = t; r < (int)kept; r += TPB_A) pool[G + r] = spool[r];
        if (t == 0) sh_nc = G + kept;
        __syncthreads();
      }
      int q = j5 >> 2, c2 = j5 & 3;
      float s = flat[j5];
      int f4 = f4base + t + q * TPB_A;
      u32 key = __float_as_uint(s);
      bool pred = false;
      if (f4 < f4end && s > CONF_T) {
        u32 bin = (key >> 16) - HB0;
        if (bin > 1023u) bin = 1023u;
        pred = (bin == hbbin);
      }
      u64 bal = __ballot(pred);
      u32 wb = 0;
      if (bal) {
        if (lane == 0) wb = atomicAdd(&sh_nc, (u32)__popcll(bal));
        wb = __shfl(wb, 0);
      }
      if (pred) {
        u32 pos = wb + (u32)__popcll(bal & ((1ULL << lane) - 1ULL));
        u32 i = (u32)(f4 * 4 + c2);
        if (pos < (u32)POOL_A)
          pool[pos] = ((u64)key << 32) | (u64)(0xFFFFFFFFu - i);
      }
      __syncthreads();
    }
    nc = sh_nc < (u32)POOL_A ? sh_nc : (u32)POOL_A;
  }

  spool[t] = 0ULL;
  u64 m0 = (t < (int)nc) ? pool[t] : 0ULL;
  u64 m1 = (t + 256 < (int)nc) ? pool[t + 256] : 0ULL;
  u64 m2 = (t + 512 < (int)nc) ? pool[t + 512] : 0ULL;
  __syncthreads();
  u32 r0 = 0, r1 = 0, r2 = 0;
  u32 k = 0;
  for (; k + 4 <= nc; k += 4) {
    u64 p0 = pool[k], p1 = pool[k + 1], p2 = pool[k + 2], p3 = pool[k + 3];
    r0 += (u32)(p0 > m0) + (u32)(p1 > m0) + (u32)(p2 > m0) + (u32)(p3 > m0);
    r1 += (u32)(p0 > m1) + (u32)(p1 > m1) + (u32)(p2 > m1) + (u32)(p3 > m1);
    r2 += (u32)(p0 > m2) + (u32)(p1 > m2) + (u32)(p2 > m2) + (u32)(p3 > m2);
  }
  for (; k < nc; ++k) {
    u64 pk = pool[k];
    r0 += (u32)(pk > m0); r1 += (u32)(pk > m1); r2 += (u32)(pk > m2);
  }
  if (m0 != 0ULL && r0 < (u32)K_) spool[r0] = m0;
  if (m1 != 0ULL && r1 < (u32)K_) spool[r1] = m1;
  if (m2 != 0ULL && r2 < (u32)K_) spool[r2] = m2;
  __syncthreads();
  if (t < K_) cand[(size_t)blockIdx.x * K_ + t] = spool[t];
}

// ---------------------------------------------------------------------------
// Kernel B: per (b,c), 512 threads. Binary-search merge of 4 sorted 200-lists
// -> decode -> split IoU bitmask (2 groups) -> wave-0 greedy scan -> full
// 200x5 tile built in LDS, written coalesced (memset fused; cls==1 blocks
// also zero their image's cls-0 plane). 640 blocks.
// ---------------------------------------------------------------------------
__global__ __launch_bounds__(TPB_N) void nms_kernel(
    const u64* __restrict__ cand,
    const float4* __restrict__ loc1,
    const float4* __restrict__ loc2,
    const float4* __restrict__ dbox,
    float* __restrict__ out)
{
  const int t = threadIdx.x;
  const int lane = t & 63;
  const int wv = t >> 6;
  const int bc = blockIdx.x;
  const int bimg = bc / NCLS;
  const int cls = 1 + (bc % NCLS);

  __shared__ u64 pool[800];              // 6.4 KB: 4 sorted desc segments
  __shared__ u64 spool[256];             // 2 KB
  __shared__ float4 bb[K_];              // 3.2 KB
  __shared__ float bar[K_];
  __shared__ u64 rowmask[K_][4];         // 6.4 KB
  __shared__ float outbuf[K_ * 5];       // 4 KB: full output tile
  __shared__ u64 validmask[4];
  __shared__ u64 keepmask[4];

  for (int i = t; i < 800; i += TPB_N) pool[i] = cand[(size_t)bc * 800 + i];
  if (t < 256) spool[t] = 0ULL;
  for (int i = t; i < K_ * 5; i += TPB_N) outbuf[i] = 0.0f;
  __syncthreads();

  // ---- merge: global rank = own rank + binary-search counts in other lists ----
#pragma unroll
  for (int a = 0; a < 2; ++a) {
    int el = t + TPB_N * a;              // covers 0..1023
    if (el < 800) {
      int sl = el / 200;
      int r = el - sl * 200;
      u64 e = pool[el];
      if (e != 0ULL) {
        u32 g = (u32)r;
#pragma unroll
        for (int o = 0; o < 4; ++o) {
          if (o != sl) {
            const u64* seg = pool + o * 200;
            u32 lo = 0, hi = 200;
#pragma unroll
            for (int s8 = 0; s8 < 8; ++s8) {
              u32 mid = (lo + hi) >> 1;
              bool gt = seg[mid] > e;
              lo = gt ? mid + 1 : lo;
              hi = gt ? hi : mid;
            }
            if (lo < hi && seg[lo] > e) ++lo;
            g += lo;
          }
        }
        if (g < (u32)K_) spool[g] = e;   // ranks distinct -> exact
      }
    }
  }
  __syncthreads();

  // ---- decode boxes for top-200 ----
  float x1 = 0.f, y1 = 0.f, x2 = 0.f, y2 = 0.f, area = 0.f, scv = 0.f;
  if (t < K_) {
    u64 e = spool[t];
    u32 kb = (u32)(e >> 32);
    if (kb != 0u) {
      scv = __uint_as_float(kb);
      u32 idx = 0xFFFFFFFFu - (u32)(e & 0xFFFFFFFFu);
      int nn = (idx < (u32)N_) ? (int)idx : (int)(idx - N_);
      float4 l = (idx < (u32)N_) ? loc1[(size_t)bimg * N_ + nn]
                                 : loc2[(size_t)bimg * N_ + nn];
      float4 d = dbox[nn];
      float cx = d.x + l.x * 0.1f * d.z;
      float cy = d.y + l.y * 0.1f * d.w;
      float w = d.z * __expf(l.z * 0.2f);
      float h = d.w * __expf(l.w * 0.2f);
      x1 = cx - w * 0.5f; y1 = cy - h * 0.5f;
      x2 = cx + w * 0.5f; y2 = cy + h * 0.5f;
      if (idx >= (u32)N_) {   // horizontal flip of second (TTA) view
        float tmp = 1.0f - x2; x2 = 1.0f - x1; x1 = tmp;
      }
      area = (x2 - x1) * (y2 - y1);
    }
    bb[t] = make_float4(x1, y1, x2, y2);
    bar[t] = area;
  }
  {
    bool myvalid = (t < K_) && (scv > CONF_T);
    u64 bal = __ballot(myvalid);
    if (lane == 0 && wv < 4) validmask[wv] = bal;
  }
  __syncthreads();

  // ---- IoU>thresh bitmask rows, split across two thread groups ----
  // group A (t<200): row t, cols 0..127 -> words 0,1
  // group B (256<=t<456): row t-256, cols 128..199 -> words 2,3
  {
    int row = -1, cb = 0;
    if (t < K_) { row = t; cb = 0; }
    else if (t >= 256 && t < 256 + K_) { row = t - 256; cb = 128; }
    if (row >= 0) {
      float4 mb = bb[row];
      float ma = bar[row];
      u64 mlo = 0, mhi = 0;
      int ce = cb ? K_ : 128;
#pragma unroll 8
      for (int k2 = cb; k2 < ce; ++k2) {
        float4 ob = bb[k2];
        float ox1 = fmaxf(mb.x, ob.x);
        float oy1 = fmaxf(mb.y, ob.y);
        float ox2 = fminf(mb.z, ob.z);
        float oy2 = fminf(mb.w, ob.w);
        float inter = fmaxf(ox2 - ox1, 0.f) * fmaxf(oy2 - oy1, 0.f);
        float uni = ma + bar[k2] - inter;
        u64 bit = (inter > NMS_T * uni) ? 1ULL : 0ULL;
        u64 sh2 = bit << (k2 & 63);
        if (k2 & 64) mhi |= sh2; else mlo |= sh2;  // bit6 selects word in pair
      }
      rowmask[row][(cb >> 6) + 0] = mlo;
      rowmask[row][(cb >> 6) + 1] = mhi;
    }
  }
  __syncthreads();

  // ---- sequential greedy scan: wave 0, batched LDS loads ----
  if (t < 64) {
    u64 v0 = validmask[0], v1 = validmask[1], v2 = validmask[2], v3 = validmask[3];
    u64 s0 = 0, s1 = 0, s2 = 0, s3 = 0;
    u64 k0 = 0, k1 = 0, k2m = 0, k3 = 0;
    for (int j0 = 0; j0 < K_; j0 += 4) {
      u64 q[4][4];
#pragma unroll
      for (int u = 0; u < 4; ++u) {
        q[u][0] = rowmask[j0 + u][0]; q[u][1] = rowmask[j0 + u][1];
        q[u][2] = rowmask[j0 + u][2]; q[u][3] = rowmask[j0 + u][3];
      }
#pragma unroll
      for (int u = 0; u < 4; ++u) {
        int j = j0 + u;
        int qw = j >> 6;
        u64 bit = 1ULL << (j & 63);
        u64 vw = (qw == 0) ? v0 : (qw == 1) ? v1 : (qw == 2) ? v2 : v3;
        u64 sw = (qw == 0) ? s0 : (qw == 1) ? s1 : (qw == 2) ? s2 : s3;
        if ((vw & bit) && !(sw & bit)) {
          s0 |= q[u][0]; s1 |= q[u][1]; s2 |= q[u][2]; s3 |= q[u][3];
          if (qw == 0) k0 |= bit; else if (qw == 1) k1 |= bit;
          else if (qw == 2) k2m |= bit; else k3 |= bit;
        }
      }
    }
    if (t == 0) { keepmask[0] = k0; keepmask[1] = k1; keepmask[2] = k2m; keepmask[3] = k3; }
  }
  __syncthreads();

  // ---- compact kept entries into LDS tile ----
  if (t < K_) {
    int q = t >> 6, bitp = t & 63;
    u64 kw = keepmask[q];
    if ((kw >> bitp) & 1ULL) {
      int pos = (int)__popcll(kw & ((1ULL << bitp) - 1ULL));
      for (int w2 = 0; w2 < q; ++w2) pos += (int)__popcll(keepmask[w2]);
      outbuf[pos * 5 + 0] = scv;
      outbuf[pos * 5 + 1] = x1;
      outbuf[pos * 5 + 2] = y1;
      outbuf[pos * 5 + 3] = x2;
      outbuf[pos * 5 + 4] = y2;
    }
  }
  __syncthreads();

  // ---- coalesced tile writeout (fused memset: zeros where not kept) ----
  {
    float4* o4 = (float4*)(out + (((size_t)bimg * C_) + cls) * K_ * 5);
    const float4* s4 = (const float4*)outbuf;
    for (int i = t; i < (K_ * 5) / 4; i += TPB_N) o4[i] = s4[i];
    if (cls == 1) {   // zero this image's class-0 plane (never populated)
      float4* z4 = (float4*)(out + ((size_t)bimg * C_) * K_ * 5);
      float4 z = make_float4(0.f, 0.f, 0.f, 0.f);
      for (int i = t; i < (K_ * 5) / 4; i += TPB_N) z4[i] = z;
    }
  }
}

extern "C" void kernel_launch(void* const* d_in, const int* in_sizes, int n_in,
                              void* d_out, int out_size, void* d_ws, size_t ws_size,
                              hipStream_t stream) {
  const float* loc1 = (const float*)d_in[0];
  const float* conf1 = (const float*)d_in[1];
  const float* loc2 = (const float*)d_in[2];
  const float* conf2 = (const float*)d_in[3];
  const float* dbox = (const float*)d_in[4];
  float* out = (float*)d_out;
  float* scores = (float*)d_ws;                              // 44,707,840 B
  u64* cand = (u64*)((char*)d_ws + 44707840);                // 640*4*200*8 B

  dim3 g1((N_ + TPB_S - 1) / TPB_S, B_, 2);
  softmax_kernel<<<g1, TPB_S, 0, stream>>>(conf1, conf2, scores);

  select_kernel<<<B_ * NCLS * 4, TPB_A, 0, stream>>>(scores, cand);

  nms_kernel<<<B_ * NCLS, TPB_N, 0, stream>>>(
      cand, (const float4*)loc1, (const float4*)loc2, (const float4*)dbox, out);
}